// Round 7
// baseline (211.151 us; speedup 1.0000x reference)
//
#include <hip/hip_runtime.h>

#define BATCH 2048
#define SQN 64
#define PCN 24
#define FEAT 16
#define HID 128
#define DOUT 256
#define TDIM 128
#define ADIM 4672
#define NSQT (BATCH*SQN)
#define NPCT (BATCH*PCN)
#define E_ADJ 420
#define E_ATT 40
#define E_ADJ_TOT (BATCH*E_ADJ)
#define E_ATT_TOT (BATCH*E_ATT)

typedef unsigned short u16;
typedef unsigned int u32;
typedef __attribute__((ext_vector_type(8))) short bf16x8;
typedef __attribute__((ext_vector_type(8))) unsigned short u16x8;
typedef __attribute__((ext_vector_type(4))) float f32x4;
typedef __attribute__((ext_vector_type(2))) unsigned int u32x2;
typedef __attribute__((ext_vector_type(4))) unsigned int u32x4;

// ---- weight fragment buffer offsets (u16 units), hi/lo split ----
#define OFF_WADJ_H 0
#define OFF_WADJ_L 16384
#define OFF_WOCC_H 32768
#define OFF_WOCC_L 49152
#define OFF_WATT_H 65536
#define OFF_WATT_L 81920
#define OFF_WDEF_H 98304
#define OFF_WDEF_L 114688
#define OFF_WREV_H 131072
#define OFF_WREV_L 147456
#define OFF_WOUT_H 163840
#define OFF_WOUT_L 196608
#define OFF_WPH_H  229376
#define OFF_WPH_L  827392
#define OFF_WINSQ_H 1425408
#define OFF_WINSQ_L 1429504
#define OFF_WINPC_H 1433600
#define OFF_WINPC_L 1437696
#define OFF_WPT_H  1441792
#define OFF_WPT_L  1474560
#define OFF_WVT_H  1507328
#define OFF_WVT_L  1540096
#define WB_TOTAL   1572864

#define K_SMEM 81920

// ---- pc LDS layout ----
#define PHP_OFF  0        // [64][512B] fp32 swz (32K; rows 24-31,56-63 unused)
#define PAH_OFF  32768    // [64][256B] (16K)
#define PAL_OFF  49152    // [64][256B] (16K)
#define PEA_OFF  65536
#define PED_OFF  65856
#define PSA_OFF  66176
#define PSD_OFF  66496
#define PRSA_OFF 66816
#define PCUA_OFF 67076
#define PCNA_OFF 67332
#define PRSD_OFF 67588
#define PCUD_OFF 67848
#define PCND_OFF 68104
#define PRVS_OFF 68360
#define PRVD_OFF 68616

// ---- fast helpers ----
__device__ __forceinline__ u32 cvtpk(float a, float b) {
    u32 r;
    asm("v_cvt_pk_bf16_f32 %0, %1, %2" : "=v"(r) : "v"(a), "v"(b));
    return r;   // lo half = bf16(a), hi half = bf16(b), RNE
}
__device__ __forceinline__ u16 f2b(float x) { return (u16)cvtpk(x, x); }
__device__ __forceinline__ float b2f(u16 h) { return __uint_as_float(((u32)h) << 16); }
__device__ __forceinline__ void split2(float x, u16& h, u16& l) {
    u32 wp = cvtpk(x, x);
    h = (u16)wp;
    float r = x - __uint_as_float(wp << 16);
    l = (u16)cvtpk(r, r);
}
__device__ __forceinline__ void split_pk(float a, float b, u32& wh, u32& wl) {
    wh = cvtpk(a, b);
    float ra = a - __uint_as_float(wh << 16);
    float rb = b - __uint_as_float(wh & 0xffff0000u);
    wl = cvtpk(ra, rb);
}
__device__ __forceinline__ float gelu_f(float x) {
    float x2 = x * x;
    float z2 = x * __builtin_fmaf(x2, 0.0713548162f, 1.5957691216f);
    float e = __expf(z2);
    return x - x * __fdividef(1.0f, e + 1.0f);
}
__device__ __forceinline__ f32x4 MFMA(bf16x8 a, bf16x8 b, f32x4 c) {
    return __builtin_amdgcn_mfma_f32_16x16x32_bf16(a, b, c, 0, 0, 0);
}
__device__ __forceinline__ bf16x8 bzero() {
    bf16x8 v = {0,0,0,0,0,0,0,0}; return v;
}
__device__ __forceinline__ void xfrag(const float* __restrict__ xrow, int g,
                                      bf16x8& ah, bf16x8& al)
{
    const f32x4 a = *(const f32x4*)(xrow + g*8);
    const f32x4 b = *(const f32x4*)(xrow + g*8 + 4);
    u32 h0,h1,h2,h3,l0,l1,l2,l3;
    split_pk(a[0], a[1], h0, l0);
    split_pk(a[2], a[3], h1, l1);
    split_pk(b[0], b[1], h2, l2);
    split_pk(b[2], b[3], h3, l3);
    u32x4 vh = {h0,h1,h2,h3};
    u32x4 vl = {l0,l1,l2,l3};
    ah = *(bf16x8*)&vh;
    al = *(bf16x8*)&vl;
}

// GEMM over K=128, NT n-tiles, RT row-tiles starting rowBase, split-bf16 3-term.
template<int NT, int RT>
__device__ __forceinline__ void gemm_nt(
    const unsigned char* Ah, const unsigned char* Al,
    const u16* __restrict__ wh, const u16* __restrict__ wl,
    int ntBase, int rowBase, int lane, int g, int lr, f32x4 (&c)[NT][RT])
{
    const int sw = lr << 4;
    #pragma unroll
    for (int ks = 0; ks < 4; ++ks) {
        const int ko = (ks*64 + g*16) ^ sw;
        #pragma unroll
        for (int ntl = 0; ntl < NT; ++ntl) {
            bf16x8 bh = *(const bf16x8*)(wh + (((ntBase+ntl)*4 + ks)*64 + lane)*8);
            bf16x8 bl = *(const bf16x8*)(wl + (((ntBase+ntl)*4 + ks)*64 + lane)*8);
            #pragma unroll
            for (int rt = 0; rt < RT; ++rt) {
                const int ro = ((rowBase+rt)*16 + lr)*256 + ko;
                bf16x8 ah = *(const bf16x8*)(Ah + ro);
                bf16x8 al = *(const bf16x8*)(Al + ro);
                c[ntl][rt] = MFMA(ah, bh, c[ntl][rt]);
                c[ntl][rt] = MFMA(al, bh, c[ntl][rt]);
                c[ntl][rt] = MFMA(ah, bl, c[ntl][rt]);
            }
        }
    }
}

// 1024-thread gather: thread owns (dst row d = t>>4, 8-col chunk cq = t&15)
__device__ __forceinline__ void gather_f32_16(
    const unsigned char* H, const int* srt, int st, int en, int cq, float (&acc)[8])
{
    for (int i = st; i < en; ++i) {
        const int s = srt[i];
        const unsigned char* rp = H + s*512;
        const int sw2 = (s & 15) << 4;
        #pragma unroll
        for (int u = 0; u < 2; ++u) {
            f32x4 v = *(const f32x4*)(rp + ((cq*32 + u*16) ^ sw2));
            acc[u*4+0] += v[0]; acc[u*4+1] += v[1];
            acc[u*4+2] += v[2]; acc[u*4+3] += v[3];
        }
    }
}
__device__ __forceinline__ void writeA_16(
    unsigned char* Ah, unsigned char* Al, int d, int cq, const float (&acc)[8])
{
    const int dw = (d & 15) << 4;
    u32 oh[4], ol[4];
    #pragma unroll
    for (int j = 0; j < 4; ++j) split_pk(acc[j*2], acc[j*2+1], oh[j], ol[j]);
    u32x4 vh = {oh[0],oh[1],oh[2],oh[3]};
    u32x4 vl = {ol[0],ol[1],ol[2],ol[3]};
    *(u32x4*)(Ah + d*256 + ((cq*16) ^ dw)) = vh;
    *(u32x4*)(Al + d*256 + ((cq*16) ^ dw)) = vl;
}

// ---------------------------------------------------------------------------
// k_prep: fragment-major hi/lo bf16 weight buffers (1536 frags).
// ---------------------------------------------------------------------------
__global__ __launch_bounds__(256) void k_prep(
    const float* __restrict__ W_adj, const float* __restrict__ W_occ,
    const float* __restrict__ W_att, const float* __restrict__ W_def,
    const float* __restrict__ W_rev, const float* __restrict__ W_out,
    const float* __restrict__ W_ph,
    const float* __restrict__ W_in_sq, const float* __restrict__ W_in_pc,
    const float* __restrict__ W_pt, const float* __restrict__ W_vt,
    u16* __restrict__ wb)
{
    int gid = blockIdx.x*256 + threadIdx.x;     // 384*256 -> 1536 frags
    int fid = gid >> 6, lane = gid & 63;
    int g8 = (lane >> 4) * 8, lr = lane & 15;
    u16x8 vh, vl;
    if (fid >= 1408) {   // W_pt / W_vt [256,128]
        int f = fid - 1408;
        int which = f >> 6, f2 = f & 63;
        const float* src = which ? W_vt : W_pt;
        int oh = which ? OFF_WVT_H : OFF_WPT_H;
        int ol = which ? OFF_WVT_L : OFF_WPT_L;
        int nt = f2 >> 3, kb = f2 & 7;
        int col = nt*16 + lr;
        #pragma unroll
        for (int j = 0; j < 8; ++j) {
            int k = kb*32 + g8 + j;
            u16 h, l; split2(src[k*TDIM + col], h, l);
            vh[j] = h; vl[j] = l;
        }
        *(u16x8*)(wb + oh + (f2*64 + lane)*8) = vh;
        *(u16x8*)(wb + ol + (f2*64 + lane)*8) = vl;
        return;
    }
    if (fid >= 1392) {   // W_in_sq / W_in_pc: K=16 padded to 32
        int f = fid - 1392;
        const float* src = (f < 8) ? W_in_sq : W_in_pc;
        int oh = (f < 8) ? OFF_WINSQ_H : OFF_WINPC_H;
        int ol = (f < 8) ? OFF_WINSQ_L : OFF_WINPC_L;
        int nt = f & 7;
        int col = nt*16 + lr;
        #pragma unroll
        for (int j = 0; j < 8; ++j) {
            int k = g8 + j;
            float v = (k < 16) ? src[k*HID + col] : 0.f;
            u16 h, l; split2(v, h, l);
            vh[j] = h; vl[j] = l;
        }
        *(u16x8*)(wb + oh + (nt*64 + lane)*8) = vh;
        *(u16x8*)(wb + ol + (nt*64 + lane)*8) = vl;
        return;
    }
    const float* src; int ld, f, oh, ol;
    if (fid < 32)       { src = W_adj; ld = HID;  f = fid;      oh = OFF_WADJ_H; ol = OFF_WADJ_L; }
    else if (fid < 64)  { src = W_occ; ld = HID;  f = fid-32;   oh = OFF_WOCC_H; ol = OFF_WOCC_L; }
    else if (fid < 96)  { src = W_att; ld = HID;  f = fid-64;   oh = OFF_WATT_H; ol = OFF_WATT_L; }
    else if (fid < 128) { src = W_def; ld = HID;  f = fid-96;   oh = OFF_WDEF_H; ol = OFF_WDEF_L; }
    else if (fid < 160) { src = W_rev; ld = HID;  f = fid-128;  oh = OFF_WREV_H; ol = OFF_WREV_L; }
    else if (fid < 224) { src = W_out; ld = DOUT; f = fid-160;  oh = OFF_WOUT_H; ol = OFF_WOUT_L; }
    else                { src = W_ph;  ld = ADIM; f = fid-224;  oh = OFF_WPH_H;  ol = OFF_WPH_L; }
    int nt = f >> 2, kb = f & 3;
    int col = nt*16 + lr;
    #pragma unroll
    for (int j = 0; j < 8; ++j) {
        int k = kb*32 + g8 + j;
        u16 h, l; split2(src[k*ld + col], h, l);
        vh[j] = h; vl[j] = l;
    }
    *(u16x8*)(wb + oh + (f*64 + lane)*8) = vh;
    *(u16x8*)(wb + ol + (f*64 + lane)*8) = vl;
}

// ---------------------------------------------------------------------------
// square-path, 1024 threads (16 waves): wave w -> (ntile n2=w>>1, row-half rh=w&1)
// ---------------------------------------------------------------------------
__device__ __forceinline__ void sq_path(
    unsigned char* SMb, int b, int t,
    const float* __restrict__ x_sq, const float* __restrict__ x_pc,
    const float* __restrict__ b_in_sq, const float* __restrict__ b_in_pc,
    const float* __restrict__ b_out,
    const int* __restrict__ ei_adj, const int* __restrict__ ei_occ,
    const u16* __restrict__ wb, float* __restrict__ shared_sq)
{
    unsigned char* Hs_h  = SMb;             // [64][256B] swz15 (later HWadjT_h [128][128B] swz7)
    unsigned char* Hs_l  = SMb + 16384;
    int*           Mint  = (int*)(SMb + 32768);  // [64][64] i32 (early)
    unsigned char* HOT_h = SMb + 32768;     // [128][64B] swz3
    unsigned char* HOT_l = SMb + 40960;
    unsigned char* Mocc  = SMb + 49152;     // [64][64B] swz3 bf16 (4K)
    unsigned char* A_h   = SMb + 32768;     // [64][256B] swz15 (epi1+)
    unsigned char* A_l   = SMb + 49152;
    unsigned char* Madj  = SMb + 65536;     // [64][128B] swz7 bf16 (8K)
    unsigned char* Hp    = SMb + 73728;     // [32][256B] swz15 bf16-hi (rows 24-31 zero)

    const int w = t >> 6, lane = t & 63, g = lane >> 4, lr = lane & 15;
    const int n2 = w >> 1, rh = w & 1, rtb = rh*2;
    const int colp = n2*16 + lr;

    // ---- ph0: zero Mint / Mocc / Hp pad rows ----
    #pragma unroll
    for (int ii = 0; ii < 4; ++ii) Mint[t + ii*1024] = 0;
    ((u32*)Mocc)[t] = 0;
    if (t < 512) ((u32*)(Hp + 6144))[t] = 0;
    __syncthreads();

    // ---- ph0b: count matrices ----
    for (int i = t; i < E_ADJ; i += 1024) {
        int s = ei_adj[b*E_ADJ + i] - b*SQN;
        int d = ei_adj[E_ADJ_TOT + b*E_ADJ + i] - b*SQN;
        atomicAdd(&Mint[d*64 + s], 1);
    }
    if (t < PCN) {
        int p = ei_occ[b*PCN + t] - b*PCN;
        int d = ei_occ[NPCT + b*PCN + t] - b*SQN;
        *(u16*)(Mocc + d*64 + ((p*2) ^ ((d&3)<<4))) = 0x3F80;  // bf16 1.0
    }
    __syncthreads();

    // ---- ph1: Mint -> Madj ; input GEMMs -> Hs hi/lo, Hp hi ----
    #pragma unroll
    for (int ii = 0; ii < 2; ++ii) {
        int i = t + ii*1024;             // 0..2047 (64 rows x 32 col-pairs)
        int row = i >> 5, cp = i & 31;
        float v0 = (float)Mint[row*64 + cp*2];
        float v1 = (float)Mint[row*64 + cp*2 + 1];
        *(u32*)(Madj + row*128 + ((cp*4) ^ ((row&7)<<4))) = cvtpk(v0, v1);
    }
    float hv[8];
    {
        const f32x4 z = {0.f,0.f,0.f,0.f};
        f32x4 ch[2] = {z,z};
        {
            bf16x8 bh = *(const bf16x8*)(wb + OFF_WINSQ_H + (n2*64 + lane)*8);
            bf16x8 bl = *(const bf16x8*)(wb + OFF_WINSQ_L + (n2*64 + lane)*8);
            #pragma unroll
            for (int rt = 0; rt < 2; ++rt) {
                bf16x8 ah = bzero(), al = bzero();
                if (g < 2) xfrag(x_sq + (b*SQN + (rtb+rt)*16 + lr)*FEAT, g, ah, al);
                ch[rt] = MFMA(ah, bh, ch[rt]);
                ch[rt] = MFMA(al, bh, ch[rt]);
                ch[rt] = MFMA(ah, bl, ch[rt]);
            }
        }
        const float bbs = b_in_sq[colp];
        #pragma unroll
        for (int rt = 0; rt < 2; ++rt)
            #pragma unroll
            for (int r = 0; r < 4; ++r) {
                const int row = (rtb+rt)*16 + g*4 + r;
                float h = gelu_f(ch[rt][r] + bbs);
                hv[rt*4 + r] = h;
                u16 hh, ll; split2(h, hh, ll);
                const int bo = row*256 + ((colp*2) ^ ((row&15)<<4));
                *(u16*)(Hs_h + bo) = hh;
                *(u16*)(Hs_l + bo) = ll;
            }
        f32x4 cp2 = z;
        {
            bf16x8 bh = *(const bf16x8*)(wb + OFF_WINPC_H + (n2*64 + lane)*8);
            bf16x8 bl = *(const bf16x8*)(wb + OFF_WINPC_L + (n2*64 + lane)*8);
            const int row0 = rh*16 + lr;
            bf16x8 ah = bzero(), al = bzero();
            if (g < 2 && row0 < PCN) xfrag(x_pc + (b*PCN + row0)*FEAT, g, ah, al);
            cp2 = MFMA(ah, bh, cp2);
            cp2 = MFMA(al, bh, cp2);
            cp2 = MFMA(ah, bl, cp2);
        }
        const float bbp = b_in_pc[colp];
        #pragma unroll
        for (int r = 0; r < 4; ++r) {
            const int row = rh*16 + g*4 + r;
            if (row < PCN) {
                float h = gelu_f(cp2[r] + bbp);
                *(u16*)(Hp + row*256 + ((colp*2) ^ ((row&15)<<4))) = f2b(h);
            }
        }
    }
    __syncthreads();  // B2

    // ---- ph5: HW GEMMs ----
    f32x4 hwj[2], hwo;
    {
        const f32x4 z = {0.f,0.f,0.f,0.f};
        hwj[0]=z; hwj[1]=z; hwo=z;
        const int sw15 = lr << 4;
        #pragma unroll
        for (int ks = 0; ks < 4; ++ks) {
            const int ko = (ks*64 + g*16) ^ sw15;
            bf16x8 bh = *(const bf16x8*)(wb + OFF_WADJ_H + ((n2*4 + ks)*64 + lane)*8);
            bf16x8 bl = *(const bf16x8*)(wb + OFF_WADJ_L + ((n2*4 + ks)*64 + lane)*8);
            #pragma unroll
            for (int rt = 0; rt < 2; ++rt) {
                const int ro = ((rtb+rt)*16 + lr)*256 + ko;
                bf16x8 ah = *(const bf16x8*)(Hs_h + ro);
                bf16x8 al = *(const bf16x8*)(Hs_l + ro);
                hwj[rt] = MFMA(ah, bh, hwj[rt]);
                hwj[rt] = MFMA(al, bh, hwj[rt]);
                hwj[rt] = MFMA(ah, bl, hwj[rt]);
            }
            bf16x8 oh = *(const bf16x8*)(wb + OFF_WOCC_H + ((n2*4 + ks)*64 + lane)*8);
            bf16x8 ol = *(const bf16x8*)(wb + OFF_WOCC_L + ((n2*4 + ks)*64 + lane)*8);
            {
                const int ro = (rh*16 + lr)*256 + ko;
                bf16x8 ah = *(const bf16x8*)(Hp + ro);
                hwo = MFMA(ah, oh, hwo);
                hwo = MFMA(ah, ol, hwo);
            }
        }
    }
    __syncthreads();  // B3

    // ---- ph5b: write HWadjT (over Hs) + HWoccT, transposed [j][s] ----
    {
        const int swj = (lr & 7) << 4;
        #pragma unroll
        for (int rt = 0; rt < 2; ++rt) {
            u32 h01, l01, h23, l23;
            split_pk(hwj[rt][0], hwj[rt][1], h01, l01);
            split_pk(hwj[rt][2], hwj[rt][3], h23, l23);
            const int off = colp*128 + (((rtb+rt)*32 + g*8) ^ swj);
            *(u32x2*)(Hs_h + off) = (u32x2){h01, h23};
            *(u32x2*)(Hs_l + off) = (u32x2){l01, l23};
        }
        const int swo = (lr & 3) << 4;
        {
            u32 h01, l01, h23, l23;
            split_pk(hwo[0], hwo[1], h01, l01);
            split_pk(hwo[2], hwo[3], h23, l23);
            const int off = colp*64 + ((rh*32 + g*8) ^ swo);
            *(u32x2*)(HOT_h + off) = (u32x2){h01, h23};
            *(u32x2*)(HOT_l + off) = (u32x2){l01, l23};
        }
    }
    __syncthreads();  // B4

    // ---- ph6: c1 = M_adj@HWadjT + M_occ@HWoccT ----
    f32x4 c1[2];
    {
        const f32x4 z = {0.f,0.f,0.f,0.f};
        c1[0]=z; c1[1]=z;
        const int swj = (lr & 7) << 4;
        #pragma unroll
        for (int ks = 0; ks < 2; ++ks) {
            const int bo = colp*128 + ((ks*64 + g*16) ^ swj);
            bf16x8 bh = *(const bf16x8*)(Hs_h + bo);
            bf16x8 bl = *(const bf16x8*)(Hs_l + bo);
            #pragma unroll
            for (int rt = 0; rt < 2; ++rt) {
                const int ao = ((rtb+rt)*16 + lr)*128 + ((ks*64 + g*16) ^ swj);
                bf16x8 am = *(const bf16x8*)(Madj + ao);
                c1[rt] = MFMA(am, bh, c1[rt]);
                c1[rt] = MFMA(am, bl, c1[rt]);
            }
        }
        const int swo = (lr & 3) << 4;
        {
            const int bo = colp*64 + ((g*16) ^ swo);
            bf16x8 bh = *(const bf16x8*)(HOT_h + bo);
            bf16x8 bl = *(const bf16x8*)(HOT_l + bo);
            #pragma unroll
            for (int rt = 0; rt < 2; ++rt) {
                const int ao = ((rtb+rt)*16 + lr)*64 + ((g*16) ^ swo);
                bf16x8 am = *(const bf16x8*)(Mocc + ao);
                c1[rt] = MFMA(am, bh, c1[rt]);
                c1[rt] = MFMA(am, bl, c1[rt]);
            }
        }
    }
    __syncthreads();  // B5

    // ---- epi1: h2 = gelu(c1 + h) -> A hi/lo ----
    #pragma unroll
    for (int rt = 0; rt < 2; ++rt)
        #pragma unroll
        for (int r = 0; r < 4; ++r) {
            const int row = (rtb+rt)*16 + g*4 + r;
            float h2 = gelu_f(c1[rt][r] + hv[rt*4 + r]);
            u16 hh, ll; split2(h2, hh, ll);
            const int bo = row*256 + ((colp*2) ^ ((row&15)<<4));
            *(u16*)(A_h + bo) = hh;
            *(u16*)(A_l + bo) = ll;
        }
    __syncthreads();  // B6

    // ---- GEMM2 (W_out, 1 ntile/wave over 16) + colsum/64 ----
    f32x4 c2[1][4];
    {
        const f32x4 z = {0.f,0.f,0.f,0.f};
        #pragma unroll
        for (int rt = 0; rt < 4; ++rt) c2[0][rt] = z;
    }
    gemm_nt<1,4>(A_h, A_l, wb + OFF_WOUT_H, wb + OFF_WOUT_L, w, 0, lane, g, lr, c2);
    {
        const int col = w*16 + lr;
        const float bias = b_out[col];
        float cs = 0.f;
        #pragma unroll
        for (int rt = 0; rt < 4; ++rt)
            #pragma unroll
            for (int r = 0; r < 4; ++r) cs += gelu_f(c2[0][rt][r] + bias);
        cs += __shfl_xor(cs, 16);
        cs += __shfl_xor(cs, 32);
        if (lane < 16) shared_sq[b*DOUT + col] = cs * (1.0f/64.0f);
    }
}

// ---------------------------------------------------------------------------
// piece-path, 1024 threads: 2 batches padded to [2][32 rows]; rh = batch.
// ---------------------------------------------------------------------------
__device__ __forceinline__ void pc_path(
    unsigned char* SMb, int pcb, int t,
    const float* __restrict__ x_sq, const float* __restrict__ x_pc,
    const float* __restrict__ b_in_sq, const float* __restrict__ b_in_pc,
    const float* __restrict__ b_out,
    const int* __restrict__ ei_att, const int* __restrict__ ei_def,
    const int* __restrict__ ei_rev,
    const u16* __restrict__ wb, float* __restrict__ shared_pc)
{
    unsigned char* Hp = SMb + PHP_OFF;
    unsigned char* Ah = SMb + PAH_OFF;
    unsigned char* Al = SMb + PAL_OFF;
    int* ea_pk = (int*)(SMb + PEA_OFF);
    int* ed_pk = (int*)(SMb + PED_OFF);
    int* srt_a = (int*)(SMb + PSA_OFF);
    int* srt_d = (int*)(SMb + PSD_OFF);
    int* rs_a  = (int*)(SMb + PRSA_OFF);
    int* cur_a = (int*)(SMb + PCUA_OFF);
    int* cnt_a = (int*)(SMb + PCNA_OFF);
    int* rs_d  = (int*)(SMb + PRSD_OFF);
    int* cur_d = (int*)(SMb + PCUD_OFF);
    int* cnt_d = (int*)(SMb + PCND_OFF);
    int* rv_s  = (int*)(SMb + PRVS_OFF);
    int* rv_d  = (int*)(SMb + PRVD_OFF);

    const int w = t >> 6, lane = t & 63, g = lane >> 4, lr = lane & 15;
    const int n2 = w >> 1, rh = w & 1, rtb = rh*2;
    const int colp = n2*16 + lr;

    // ---- ph0 ----
    for (int i = t; i < 2*E_ATT; i += 1024) {
        int sb = (i >= E_ATT) ? 1 : 0;
        int e = i - sb*E_ATT;
        int gb = pcb*2 + sb;
        int ro = 32*sb - gb*PCN;
        int s = ei_att[gb*E_ATT + e] + ro;
        int d = ei_att[E_ATT_TOT + gb*E_ATT + e] + ro;
        ea_pk[i] = s | (d << 16);
        s = ei_def[gb*E_ATT + e] + ro;
        d = ei_def[E_ATT_TOT + gb*E_ATT + e] + ro;
        ed_pk[i] = s | (d << 16);
    }
    if (t < 64) {
        int sb = t >> 5, pr = t & 31, gb = pcb*2 + sb;
        if (pr < PCN) {
            rv_s[t] = ei_rev[gb*PCN + pr];
            rv_d[t] = ei_rev[NPCT + gb*PCN + pr] - gb*PCN + 32*sb;
        } else { rv_s[t] = 0; rv_d[t] = 0; }
        cnt_a[t] = 0; cnt_d[t] = 0;
    }
    __syncthreads();

    // ---- ph1: counts ----
    for (int i = t; i < 2*E_ATT; i += 1024) {
        atomicAdd(&cnt_a[ea_pk[i] >> 16], 1);
        atomicAdd(&cnt_d[ed_pk[i] >> 16], 1);
    }
    __syncthreads();

    // ---- ph2: scans ----
    if (t < 64) {
        int v = cnt_a[t], o0 = v;
        for (int o = 1; o < 64; o <<= 1) { int u = __shfl_up(v, o); if (t >= o) v += u; }
        rs_a[t+1] = v; cur_a[t] = v - o0; if (t == 0) rs_a[0] = 0;
    } else if (t < 128) {
        int l = t - 64;
        int v = cnt_d[l], o0 = v;
        for (int o = 1; o < 64; o <<= 1) { int u = __shfl_up(v, o); if (l >= o) v += u; }
        rs_d[l+1] = v; cur_d[l] = v - o0; if (l == 0) rs_d[0] = 0;
    }
    __syncthreads();

    // ---- ph3: place + input GEMMs (hp -> Hp fp32 + regs; rev -> A hi/lo) ----
    for (int i = t; i < 2*E_ATT; i += 1024) {
        int pk = ea_pk[i];
        int p = atomicAdd(&cur_a[pk >> 16], 1); srt_a[p] = pk & 0xffff;
        pk = ed_pk[i];
        p = atomicAdd(&cur_d[pk >> 16], 1); srt_d[p] = pk & 0xffff;
    }
    float hv[8];
    {
        const f32x4 z = {0.f,0.f,0.f,0.f};
        f32x4 cp[2] = {z,z};
        {
            bf16x8 bh = *(const bf16x8*)(wb + OFF_WINPC_H + (n2*64 + lane)*8);
            bf16x8 bl = *(const bf16x8*)(wb + OFF_WINPC_L + (n2*64 + lane)*8);
            #pragma unroll
            for (int rt = 0; rt < 2; ++rt) {
                const int pr = rt*16 + lr;
                bf16x8 ah = bzero(), al = bzero();
                if (g < 2 && pr < PCN)
                    xfrag(x_pc + ((pcb*2 + rh)*PCN + pr)*FEAT, g, ah, al);
                cp[rt] = MFMA(ah, bh, cp[rt]);
                cp[rt] = MFMA(al, bh, cp[rt]);
                cp[rt] = MFMA(ah, bl, cp[rt]);
            }
        }
        const float bbp = b_in_pc[colp];
        #pragma unroll
        for (int rt = 0; rt < 2; ++rt)
            #pragma unroll
            for (int r = 0; r < 4; ++r) {
                const int pr = rt*16 + g*4 + r;
                float h = gelu_f(cp[rt][r] + bbp);
                hv[rt*4 + r] = h;
                if (pr < PCN) {
                    const int row = rh*32 + pr;
                    *(float*)(Hp + row*512 + ((colp*4) ^ ((row&15)<<4))) = h;
                }
            }
        f32x4 cr[2] = {z,z};
        {
            bf16x8 bh = *(const bf16x8*)(wb + OFF_WINSQ_H + (n2*64 + lane)*8);
            bf16x8 bl = *(const bf16x8*)(wb + OFF_WINSQ_L + (n2*64 + lane)*8);
            #pragma unroll
            for (int rt = 0; rt < 2; ++rt) {
                const int pr = rt*16 + lr;
                bf16x8 ah = bzero(), al = bzero();
                if (g < 2 && pr < PCN) {
                    int gr = rv_s[rh*32 + pr];
                    xfrag(x_sq + gr*FEAT, g, ah, al);
                }
                cr[rt] = MFMA(ah, bh, cr[rt]);
                cr[rt] = MFMA(al, bh, cr[rt]);
                cr[rt] = MFMA(ah, bl, cr[rt]);
            }
        }
        const float bbs = b_in_sq[colp];
        #pragma unroll
        for (int rt = 0; rt < 2; ++rt)
            #pragma unroll
            for (int r = 0; r < 4; ++r) {
                const int pr = rt*16 + g*4 + r;
                if (pr < PCN) {
                    const int dr = rv_d[rh*32 + pr];
                    float h = gelu_f(cr[rt][r] + bbs);
                    u16 hh, ll; split2(h, hh, ll);
                    const int bo = dr*256 + ((colp*2) ^ ((dr&15)<<4));
                    *(u16*)(Ah + bo) = hh;
                    *(u16*)(Al + bo) = ll;
                }
            }
    }
    __syncthreads();

    // ---- GEMM1c (W_rev) ----
    f32x4 c1[1][2];
    {
        const f32x4 z = {0.f,0.f,0.f,0.f};
        c1[0][0] = z; c1[0][1] = z;
    }
    gemm_nt<1,2>(Ah, Al, wb + OFF_WREV_H, wb + OFF_WREV_L, n2, rtb, lane, g, lr, c1);
    __syncthreads();

    // ---- att gather -> A ----
    {
        const int d = t >> 4, cq = t & 15;
        float acc[8];
        #pragma unroll
        for (int i = 0; i < 8; ++i) acc[i] = 0.f;
        gather_f32_16(Hp, srt_a, rs_a[d], rs_a[d+1], cq, acc);
        writeA_16(Ah, Al, d, cq, acc);
    }
    __syncthreads();

    gemm_nt<1,2>(Ah, Al, wb + OFF_WATT_H, wb + OFF_WATT_L, n2, rtb, lane, g, lr, c1);
    __syncthreads();

    // ---- def gather -> A ----
    {
        const int d = t >> 4, cq = t & 15;
        float acc[8];
        #pragma unroll
        for (int i = 0; i < 8; ++i) acc[i] = 0.f;
        gather_f32_16(Hp, srt_d, rs_d[d], rs_d[d+1], cq, acc);
        writeA_16(Ah, Al, d, cq, acc);
    }
    __syncthreads();

    gemm_nt<1,2>(Ah, Al, wb + OFF_WDEF_H, wb + OFF_WDEF_L, n2, rtb, lane, g, lr, c1);
    __syncthreads();

    // ---- epi1: h2 = gelu(hp + agg) -> A (pad rows harmless garbage) ----
    #pragma unroll
    for (int rt = 0; rt < 2; ++rt)
        #pragma unroll
        for (int r = 0; r < 4; ++r) {
            const int row = rh*32 + rt*16 + g*4 + r;
            float h2 = gelu_f(c1[0][rt][r] + hv[rt*4 + r]);
            u16 hh, ll; split2(h2, hh, ll);
            const int bo = row*256 + ((colp*2) ^ ((row&15)<<4));
            *(u16*)(Ah + bo) = hh;
            *(u16*)(Al + bo) = ll;
        }
    __syncthreads();

    // ---- GEMM2 (W_out, 2 ntiles/wave) + per-batch colsum/24 ----
    f32x4 c2[2][2];
    {
        const f32x4 z = {0.f,0.f,0.f,0.f};
        c2[0][0]=z; c2[0][1]=z; c2[1][0]=z; c2[1][1]=z;
    }
    gemm_nt<2,2>(Ah, Al, wb + OFF_WOUT_H, wb + OFF_WOUT_L, n2*2, rtb, lane, g, lr, c2);
    #pragma unroll
    for (int ntl = 0; ntl < 2; ++ntl) {
        const int col = (n2*2 + ntl)*16 + lr;
        const float bias = b_out[col];
        float cs = 0.f;
        #pragma unroll
        for (int r = 0; r < 4; ++r) cs += gelu_f(c2[ntl][0][r] + bias);
        {
            float tt = 0.f;
            #pragma unroll
            for (int r = 0; r < 4; ++r) tt += gelu_f(c2[ntl][1][r] + bias);
            cs += (g < 2) ? tt : 0.f;   // rows 16-23 valid only
        }
        cs += __shfl_xor(cs, 16);
        cs += __shfl_xor(cs, 32);
        if (lane < 16) shared_pc[(pcb*2 + rh)*DOUT + col] = cs * (1.0f/PCN);
    }
}

// ---------------------------------------------------------------------------
__global__ __launch_bounds__(1024, 8) void k_main(
    const float* __restrict__ x_sq, const float* __restrict__ x_pc,
    const float* __restrict__ b_in_sq, const float* __restrict__ b_in_pc,
    const float* __restrict__ b_out,
    const int* __restrict__ ei_adj, const int* __restrict__ ei_occ,
    const int* __restrict__ ei_att, const int* __restrict__ ei_def,
    const int* __restrict__ ei_rev,
    const u16* __restrict__ wb,
    float* __restrict__ shared_sq, float* __restrict__ shared_pc)
{
    extern __shared__ __align__(16) unsigned char SMb[];
    const int bid = blockIdx.x;
    const int grp = bid / 3, rem = bid - grp*3;
    if (rem < 2) {
        sq_path(SMb, grp*2 + rem, threadIdx.x, x_sq, x_pc, b_in_sq, b_in_pc,
                b_out, ei_adj, ei_occ, wb, shared_sq);
    } else {
        pc_path(SMb, grp, threadIdx.x, x_sq, x_pc, b_in_sq, b_in_pc,
                b_out, ei_att, ei_def, ei_rev, wb, shared_pc);
    }
}

// ---------------------------------------------------------------------------
// k_head (MFMA): 64 blocks x 32 rows, 512 threads.
// ---------------------------------------------------------------------------
__global__ __launch_bounds__(512) void k_head(
    const float* __restrict__ shared_sq, const float* __restrict__ shared_pc,
    const u16* __restrict__ wb,
    const float* __restrict__ b_pt, const float* __restrict__ b_vt,
    const float* __restrict__ W_vh, const float* __restrict__ b_vh,
    u16* __restrict__ tpol_h, u16* __restrict__ tpol_l, float* __restrict__ out_value)
{
    __shared__ __align__(16) unsigned char SH[33792];
    unsigned char* Ah = SH;             // [32][512B] swz15
    unsigned char* Al = SH + 16384;
    float* vpart = (float*)(SH + 32768);  // [32][8]

    const int t = threadIdx.x;
    const int w = t >> 6, lane = t & 63, g = lane >> 4, lr = lane & 15;
    const int rbase = blockIdx.x * 32;

    // ---- stage S = shared_sq + shared_pc as hi/lo bf16 ----
    {
        const int row = t >> 4, c0 = (t & 15) * 16;
        const float* s1 = shared_sq + (size_t)(rbase + row)*DOUT + c0;
        const float* s2 = shared_pc + (size_t)(rbase + row)*DOUT + c0;
        const int sw = (row & 15) << 4;
        #pragma unroll
        for (int cc = 0; cc < 2; ++cc) {
            f32x4 a = *(const f32x4*)(s1 + cc*8);
            f32x4 b = *(const f32x4*)(s2 + cc*8);
            f32x4 a2 = *(const f32x4*)(s1 + cc*8 + 4);
            f32x4 b2 = *(const f32x4*)(s2 + cc*8 + 4);
            float v0=a[0]+b[0], v1=a[1]+b[1], v2=a[2]+b[2], v3=a[3]+b[3];
            float v4=a2[0]+b2[0], v5=a2[1]+b2[1], v6=a2[2]+b2[2], v7=a2[3]+b2[3];
            u32 h0,h1,h2,h3,l0,l1,l2,l3;
            split_pk(v0,v1,h0,l0); split_pk(v2,v3,h1,l1);
            split_pk(v4,v5,h2,l2); split_pk(v6,v7,h3,l3);
            u32x4 vh = {h0,h1,h2,h3};
            u32x4 vl = {l0,l1,l2,l3};
            *(u32x4*)(Ah + row*512 + ((c0*2 + cc*16) ^ sw)) = vh;
            *(u32x4*)(Al + row*512 + ((c0*2 + cc*16) ^ sw)) = vl;
        }
    }
    __syncthreads();

    // ---- GEMMs: S@W_pt and S@W_vt (K=256, nt=w for both) ----
    f32x4 cpt[2], cvt[2];
    {
        const f32x4 z = {0.f,0.f,0.f,0.f};
        cpt[0]=z; cpt[1]=z; cvt[0]=z; cvt[1]=z;
        const int sw = lr << 4;
        #pragma unroll
        for (int ks = 0; ks < 8; ++ks) {
            const int ko = (ks*64 + g*16) ^ sw;
            bf16x8 ph_ = *(const bf16x8*)(wb + OFF_WPT_H + ((w*8 + ks)*64 + lane)*8);
            bf16x8 pl_ = *(const bf16x8*)(wb + OFF_WPT_L + ((w*8 + ks)*64 + lane)*8);
            bf16x8 vh_ = *(const bf16x8*)(wb + OFF_WVT_H + ((w*8 + ks)*64 + lane)*8);
            bf16x8 vl_ = *(const bf16x8*)(wb + OFF_WVT_L + ((w*8 + ks)*64 + lane)*8);
            #pragma unroll
            for (int rt = 0; rt < 2; ++rt) {
                const int ao = (rt*16 + lr)*512 + ko;
                bf16x8 ah = *(const bf16x8*)(Ah + ao);
                bf16x8 al = *(const bf16x8*)(Al + ao);
                cpt[rt] = MFMA(ah, ph_, cpt[rt]);
                cpt[rt] = MFMA(al, ph_, cpt[rt]);
                cpt[rt] = MFMA(ah, pl_, cpt[rt]);
                cvt[rt] = MFMA(ah, vh_, cvt[rt]);
                cvt[rt] = MFMA(al, vh_, cvt[rt]);
                cvt[rt] = MFMA(ah, vl_, cvt[rt]);
            }
        }
    }

    // ---- epilogues ----
    {
        const int col = w*16 + lr;
        const float bpt = b_pt[col], bvt = b_vt[col], wvh = W_vh[col];
        #pragma unroll
        for (int rt = 0; rt < 2; ++rt)
            #pragma unroll
            for (int r = 0; r < 4; ++r) {
                const int row = rt*16 + g*4 + r;
                float tv = gelu_f(cpt[rt][r] + bpt);
                u16 th, tl; split2(tv, th, tl);
                tpol_h[(size_t)(rbase + row)*TDIM + col] = th;
                tpol_l[(size_t)(rbase + row)*TDIM + col] = tl;
                float vv = gelu_f(cvt[rt][r] + bvt) * wvh;
                vv += __shfl_xor(vv, 1);
                vv += __shfl_xor(vv, 2);
                vv += __shfl_xor(vv, 4);
                vv += __shfl_xor(vv, 8);
                if (lr == 0) vpart[row*8 + w] = vv;
            }
    }
    __syncthreads();
    if (t < 32) {
        float s = 0.f;
        #pragma unroll
        for (int j = 0; j < 8; ++j) s += vpart[t*8 + j];
        out_value[rbase + t] = tanhf(s + b_vh[0]);
    }
}

// ---------------------------------------------------------------------------
// k_pol: policy = tpol @ W_ph + b_ph, split-bf16 MFMA. grid (73, 32).
// ---------------------------------------------------------------------------
__global__ __launch_bounds__(256) void k_pol(
    const u16* __restrict__ tpol_h, const u16* __restrict__ tpol_l,
    const u16* __restrict__ wb, const float* __restrict__ b_ph,
    float* __restrict__ pol)
{
    const u16* wph_h = wb + OFF_WPH_H;
    const u16* wph_l = wb + OFF_WPH_L;
    const int t = threadIdx.x, w = t >> 6, lane = t & 63, g = lane >> 4, lr = lane & 15;
    const int nt = blockIdx.x*4 + w;       // 0..291
    const int rbase = blockIdx.y*64;
    f32x4 acc[4];
    const f32x4 z = {0.f,0.f,0.f,0.f};
    #pragma unroll
    for (int rt = 0; rt < 4; ++rt) acc[rt] = z;
    #pragma unroll
    for (int ks = 0; ks < 4; ++ks) {
        bf16x8 bh = *(const bf16x8*)(wph_h + ((nt*4 + ks)*64 + lane)*8);
        bf16x8 bl = *(const bf16x8*)(wph_l + ((nt*4 + ks)*64 + lane)*8);
        #pragma unroll
        for (int rt = 0; rt < 4; ++rt) {
            const int ro = (rbase + rt*16 + lr)*TDIM + ks*32 + g*8;
            bf16x8 ah = *(const bf16x8*)(tpol_h + ro);
            bf16x8 al = *(const bf16x8*)(tpol_l + ro);
            acc[rt] = MFMA(ah, bh, acc[rt]);
            acc[rt] = MFMA(al, bh, acc[rt]);
            acc[rt] = MFMA(ah, bl, acc[rt]);
        }
    }
    const float bias = b_ph[nt*16 + lr];
    #pragma unroll
    for (int rt = 0; rt < 4; ++rt)
        #pragma unroll
        for (int r = 0; r < 4; ++r) {
            int row = rbase + rt*16 + g*4 + r;
            pol[(size_t)row*ADIM + nt*16 + lr] = acc[rt][r] + bias;
        }
}

// ---------------------------------------------------------------------------
extern "C" void kernel_launch(void* const* d_in, const int* in_sizes, int n_in,
                              void* d_out, int out_size, void* d_ws, size_t ws_size,
                              hipStream_t stream) {
    (void)in_sizes; (void)n_in; (void)out_size; (void)ws_size;
    const float* x_sq    = (const float*)d_in[0];
    const float* x_pc    = (const float*)d_in[1];
    const float* W_in_sq = (const float*)d_in[2];
    const float* b_in_sq = (const float*)d_in[3];
    const float* W_in_pc = (const float*)d_in[4];
    const float* b_in_pc = (const float*)d_in[5];
    const float* W_adj   = (const float*)d_in[6];
    const float* W_occ   = (const float*)d_in[7];
    const float* W_att   = (const float*)d_in[8];
    const float* W_def   = (const float*)d_in[9];
    const float* W_rev   = (const float*)d_in[10];
    const float* W_out   = (const float*)d_in[11];
    const float* b_out   = (const float*)d_in[12];
    const float* W_pt    = (const float*)d_in[13];
    const float* b_pt    = (const float*)d_in[14];
    const float* W_vt    = (const float*)d_in[15];
    const float* b_vt    = (const float*)d_in[16];
    const float* W_ph    = (const float*)d_in[17];
    const float* b_ph    = (const float*)d_in[18];
    const float* W_vh    = (const float*)d_in[19];
    const float* b_vh    = (const float*)d_in[20];
    const int* ei_adj    = (const int*)d_in[21];
    const int* ei_occ    = (const int*)d_in[22];
    const int* ei_att    = (const int*)d_in[23];
    const int* ei_def    = (const int*)d_in[24];
    const int* ei_rev    = (const int*)d_in[25];

    float* out = (float*)d_out;
    float* pol = out;
    float* val = out + (size_t)BATCH * ADIM;

    float* shared_sq = (float*)d_ws;                     // [2048][256] f32
    float* shared_pc = shared_sq + BATCH*DOUT;           // [2048][256] f32
    u16* tpol_h = (u16*)(shared_pc + BATCH*DOUT);        // [2048][128] bf16
    u16* tpol_l = tpol_h + BATCH*TDIM;
    u16* wb     = tpol_l + BATCH*TDIM;                   // WB_TOTAL u16

    hipFuncSetAttribute((const void*)k_main,
                        hipFuncAttributeMaxDynamicSharedMemorySize, K_SMEM);

    k_prep<<<384, 256, 0, stream>>>(W_adj, W_occ, W_att, W_def, W_rev, W_out, W_ph,
                                    W_in_sq, W_in_pc, W_pt, W_vt, wb);
    k_main<<<3072, 1024, K_SMEM, stream>>>(x_sq, x_pc, b_in_sq, b_in_pc, b_out,
                                           ei_adj, ei_occ, ei_att, ei_def, ei_rev,
                                           wb, shared_sq, shared_pc);
    k_head<<<64, 512, 0, stream>>>(shared_sq, shared_pc, wb, b_pt, b_vt, W_vh, b_vh,
                                   tpol_h, tpol_l, val);
    k_pol<<<dim3(ADIM/64, BATCH/64), 256, 0, stream>>>(tpol_h, tpol_l, wb, b_ph, pol);
}

// Round 8
// 187.719 us; speedup vs baseline: 1.1248x; 1.1248x over previous
//
#include <hip/hip_runtime.h>

#define BATCH 2048
#define SQN 64
#define PCN 24
#define FEAT 16
#define HID 128
#define DOUT 256
#define TDIM 128
#define ADIM 4672
#define NSQT (BATCH*SQN)
#define NPCT (BATCH*PCN)
#define E_ADJ 420
#define E_ATT 40
#define E_ADJ_TOT (BATCH*E_ADJ)
#define E_ATT_TOT (BATCH*E_ATT)

typedef unsigned short u16;
typedef unsigned int u32;
typedef __attribute__((ext_vector_type(8))) short bf16x8;
typedef __attribute__((ext_vector_type(8))) unsigned short u16x8;
typedef __attribute__((ext_vector_type(4))) float f32x4;
typedef __attribute__((ext_vector_type(2))) unsigned int u32x2;
typedef __attribute__((ext_vector_type(4))) unsigned int u32x4;

// ---- weight fragment buffer offsets (u16 units), hi/lo split ----
#define OFF_WADJ_H 0
#define OFF_WADJ_L 16384
#define OFF_WOCC_H 32768
#define OFF_WOCC_L 49152
#define OFF_WATT_H 65536
#define OFF_WATT_L 81920
#define OFF_WDEF_H 98304
#define OFF_WDEF_L 114688
#define OFF_WREV_H 131072
#define OFF_WREV_L 147456
#define OFF_WOUT_H 163840
#define OFF_WOUT_L 196608
#define OFF_WPH_H  229376
#define OFF_WPH_L  827392
#define OFF_WINSQ_H 1425408
#define OFF_WINSQ_L 1429504
#define OFF_WINPC_H 1433600
#define OFF_WINPC_L 1437696
#define OFF_WPT_H  1441792
#define OFF_WPT_L  1474560
#define OFF_WVT_H  1507328
#define OFF_WVT_L  1540096
#define WB_TOTAL   1572864

#define K_SMEM 81920

// ---- pc LDS layout ----
#define PHP_OFF  0        // [48][512B] fp32 swizzled
#define PAH_OFF  24576    // [48][256B]
#define PAL_OFF  36864    // [48][256B]
#define PEA_OFF  49152    // 80 packed att
#define PED_OFF  49472    // 80 packed def
#define PSA_OFF  49792    // 80
#define PSD_OFF  50112    // 80
#define PRSA_OFF 50432    // 65
#define PCUA_OFF 50692    // 64
#define PCNA_OFF 50948    // 64
#define PRSD_OFF 51204    // 65
#define PCUD_OFF 51464    // 64
#define PCND_OFF 51720    // 64
#define PRVS_OFF 51976    // 48
#define PRVD_OFF 52168    // 48

// ---- fast helpers ----
__device__ __forceinline__ u32 cvtpk(float a, float b) {
    u32 r;
    asm("v_cvt_pk_bf16_f32 %0, %1, %2" : "=v"(r) : "v"(a), "v"(b));
    return r;   // lo half = bf16(a), hi half = bf16(b), RNE
}
__device__ __forceinline__ u16 f2b(float x) { return (u16)cvtpk(x, x); }
__device__ __forceinline__ float b2f(u16 h) { return __uint_as_float(((u32)h) << 16); }
__device__ __forceinline__ void split2(float x, u16& h, u16& l) {
    u32 wp = cvtpk(x, x);
    h = (u16)wp;
    float r = x - __uint_as_float(wp << 16);
    l = (u16)cvtpk(r, r);
}
__device__ __forceinline__ void split_pk(float a, float b, u32& wh, u32& wl) {
    wh = cvtpk(a, b);
    float ra = a - __uint_as_float(wh << 16);
    float rb = b - __uint_as_float(wh & 0xffff0000u);
    wl = cvtpk(ra, rb);
}
__device__ __forceinline__ float gelu_f(float x) {
    float x2 = x * x;
    float z2 = x * __builtin_fmaf(x2, 0.0713548162f, 1.5957691216f);
    float e = __expf(z2);
    return x - x * __fdividef(1.0f, e + 1.0f);
}
__device__ __forceinline__ f32x4 MFMA(bf16x8 a, bf16x8 b, f32x4 c) {
    return __builtin_amdgcn_mfma_f32_16x16x32_bf16(a, b, c, 0, 0, 0);
}
__device__ __forceinline__ bf16x8 bzero() {
    bf16x8 v = {0,0,0,0,0,0,0,0}; return v;
}
__device__ __forceinline__ void xfrag(const float* __restrict__ xrow, int g,
                                      bf16x8& ah, bf16x8& al)
{
    const f32x4 a = *(const f32x4*)(xrow + g*8);
    const f32x4 b = *(const f32x4*)(xrow + g*8 + 4);
    u32 h0,h1,h2,h3,l0,l1,l2,l3;
    split_pk(a[0], a[1], h0, l0);
    split_pk(a[2], a[3], h1, l1);
    split_pk(b[0], b[1], h2, l2);
    split_pk(b[2], b[3], h3, l3);
    u32x4 vh = {h0,h1,h2,h3};
    u32x4 vl = {l0,l1,l2,l3};
    ah = *(bf16x8*)&vh;
    al = *(bf16x8*)&vl;
}

// GEMM over K=128, NT n-tiles per wave starting ntBase, split-bf16 3-term.
template<int NT, int RT>
__device__ __forceinline__ void gemm_nt(
    const unsigned char* Ah, const unsigned char* Al,
    const u16* __restrict__ wh, const u16* __restrict__ wl,
    int ntBase, int lane, int g, int lr, f32x4 (&c)[NT][RT])
{
    const int sw = lr << 4;
    #pragma unroll
    for (int ks = 0; ks < 4; ++ks) {
        const int ko = (ks*64 + g*16) ^ sw;
        #pragma unroll
        for (int ntl = 0; ntl < NT; ++ntl) {
            bf16x8 bh = *(const bf16x8*)(wh + (((ntBase+ntl)*4 + ks)*64 + lane)*8);
            bf16x8 bl = *(const bf16x8*)(wl + (((ntBase+ntl)*4 + ks)*64 + lane)*8);
            #pragma unroll
            for (int rt = 0; rt < RT; ++rt) {
                const int ro = (rt*16 + lr)*256 + ko;
                bf16x8 ah = *(const bf16x8*)(Ah + ro);
                bf16x8 al = *(const bf16x8*)(Al + ro);
                c[ntl][rt] = MFMA(ah, bh, c[ntl][rt]);
                c[ntl][rt] = MFMA(al, bh, c[ntl][rt]);
                c[ntl][rt] = MFMA(ah, bl, c[ntl][rt]);
            }
        }
    }
}

// 512-thread gather: thread owns (dst row d = t>>3, 16-col chunk cq8 = t&7)
__device__ __forceinline__ void gather_f32_8(
    const unsigned char* H, const int* srt, int st, int en, int cq8, float (&acc)[16])
{
    for (int i = st; i < en; ++i) {
        const int s = srt[i];
        const unsigned char* rp = H + s*512;
        const int sw2 = (s & 15) << 4;
        #pragma unroll
        for (int u = 0; u < 4; ++u) {
            f32x4 v = *(const f32x4*)(rp + ((cq8*64 + u*16) ^ sw2));
            acc[u*4+0] += v[0]; acc[u*4+1] += v[1];
            acc[u*4+2] += v[2]; acc[u*4+3] += v[3];
        }
    }
}
__device__ __forceinline__ void writeA_8(
    unsigned char* Ah, unsigned char* Al, int d, int cq8, const float (&acc)[16])
{
    unsigned char* wh = Ah + d*256;
    unsigned char* wl = Al + d*256;
    const int dw = (d & 15) << 4;
    #pragma unroll
    for (int u = 0; u < 2; ++u) {
        u32 oh[4], ol[4];
        #pragma unroll
        for (int j = 0; j < 4; ++j)
            split_pk(acc[u*8 + j*2], acc[u*8 + j*2 + 1], oh[j], ol[j]);
        u32x4 vh = {oh[0], oh[1], oh[2], oh[3]};
        u32x4 vl = {ol[0], ol[1], ol[2], ol[3]};
        *(u32x4*)(wh + ((cq8*32 + u*16) ^ dw)) = vh;
        *(u32x4*)(wl + ((cq8*32 + u*16) ^ dw)) = vl;
    }
}

// ---------------------------------------------------------------------------
// k_prep: fragment-major hi/lo bf16 weight buffers (1536 frags).
// ---------------------------------------------------------------------------
__global__ __launch_bounds__(256) void k_prep(
    const float* __restrict__ W_adj, const float* __restrict__ W_occ,
    const float* __restrict__ W_att, const float* __restrict__ W_def,
    const float* __restrict__ W_rev, const float* __restrict__ W_out,
    const float* __restrict__ W_ph,
    const float* __restrict__ W_in_sq, const float* __restrict__ W_in_pc,
    const float* __restrict__ W_pt, const float* __restrict__ W_vt,
    u16* __restrict__ wb)
{
    int gid = blockIdx.x*256 + threadIdx.x;     // 384*256 -> 1536 frags
    int fid = gid >> 6, lane = gid & 63;
    int g8 = (lane >> 4) * 8, lr = lane & 15;
    u16x8 vh, vl;
    if (fid >= 1408) {   // W_pt / W_vt [256,128]
        int f = fid - 1408;
        int which = f >> 6, f2 = f & 63;
        const float* src = which ? W_vt : W_pt;
        int oh = which ? OFF_WVT_H : OFF_WPT_H;
        int ol = which ? OFF_WVT_L : OFF_WPT_L;
        int nt = f2 >> 3, kb = f2 & 7;
        int col = nt*16 + lr;
        #pragma unroll
        for (int j = 0; j < 8; ++j) {
            int k = kb*32 + g8 + j;
            u16 h, l; split2(src[k*TDIM + col], h, l);
            vh[j] = h; vl[j] = l;
        }
        *(u16x8*)(wb + oh + (f2*64 + lane)*8) = vh;
        *(u16x8*)(wb + ol + (f2*64 + lane)*8) = vl;
        return;
    }
    if (fid >= 1392) {   // W_in_sq / W_in_pc: K=16 padded to 32
        int f = fid - 1392;
        const float* src = (f < 8) ? W_in_sq : W_in_pc;
        int oh = (f < 8) ? OFF_WINSQ_H : OFF_WINPC_H;
        int ol = (f < 8) ? OFF_WINSQ_L : OFF_WINPC_L;
        int nt = f & 7;
        int col = nt*16 + lr;
        #pragma unroll
        for (int j = 0; j < 8; ++j) {
            int k = g8 + j;
            float v = (k < 16) ? src[k*HID + col] : 0.f;
            u16 h, l; split2(v, h, l);
            vh[j] = h; vl[j] = l;
        }
        *(u16x8*)(wb + oh + (nt*64 + lane)*8) = vh;
        *(u16x8*)(wb + ol + (nt*64 + lane)*8) = vl;
        return;
    }
    const float* src; int ld, f, oh, ol;
    if (fid < 32)       { src = W_adj; ld = HID;  f = fid;      oh = OFF_WADJ_H; ol = OFF_WADJ_L; }
    else if (fid < 64)  { src = W_occ; ld = HID;  f = fid-32;   oh = OFF_WOCC_H; ol = OFF_WOCC_L; }
    else if (fid < 96)  { src = W_att; ld = HID;  f = fid-64;   oh = OFF_WATT_H; ol = OFF_WATT_L; }
    else if (fid < 128) { src = W_def; ld = HID;  f = fid-96;   oh = OFF_WDEF_H; ol = OFF_WDEF_L; }
    else if (fid < 160) { src = W_rev; ld = HID;  f = fid-128;  oh = OFF_WREV_H; ol = OFF_WREV_L; }
    else if (fid < 224) { src = W_out; ld = DOUT; f = fid-160;  oh = OFF_WOUT_H; ol = OFF_WOUT_L; }
    else                { src = W_ph;  ld = ADIM; f = fid-224;  oh = OFF_WPH_H;  ol = OFF_WPH_L; }
    int nt = f >> 2, kb = f & 3;
    int col = nt*16 + lr;
    #pragma unroll
    for (int j = 0; j < 8; ++j) {
        int k = kb*32 + g8 + j;
        u16 h, l; split2(src[k*ld + col], h, l);
        vh[j] = h; vl[j] = l;
    }
    *(u16x8*)(wb + oh + (f*64 + lane)*8) = vh;
    *(u16x8*)(wb + ol + (f*64 + lane)*8) = vl;
}

// ---------------------------------------------------------------------------
// square-path (512 threads, 8 waves): segment-sums as M-matrix MFMA.
// LDS (81920B): [0,32K) Hs hi/lo -> HWadjT hi/lo ; [32K,64K) Mint -> HWoccT+Mocc -> A hi/lo ;
//               [64K,72K) M_adj ; [72K,80K) Hp(32 rows, bf16-hi)
// ---------------------------------------------------------------------------
__device__ __forceinline__ void sq_path(
    unsigned char* SMb, int b, int t,
    const float* __restrict__ x_sq, const float* __restrict__ x_pc,
    const float* __restrict__ b_in_sq, const float* __restrict__ b_in_pc,
    const float* __restrict__ b_out,
    const int* __restrict__ ei_adj, const int* __restrict__ ei_occ,
    const u16* __restrict__ wb, float* __restrict__ shared_sq)
{
    unsigned char* Hs_h  = SMb;             // [64][256B] swz15 (later HWadjT_h [128][128B] swz7)
    unsigned char* Hs_l  = SMb + 16384;
    int*           Mint  = (int*)(SMb + 32768);  // [64][64] i32 (early)
    unsigned char* HOT_h = SMb + 32768;     // [128][64B] swz3
    unsigned char* HOT_l = SMb + 40960;
    unsigned char* Mocc  = SMb + 49152;     // [64][64B] swz3 bf16 (4K)
    unsigned char* A_h   = SMb + 32768;     // [64][256B] swz15 (epi1+)
    unsigned char* A_l   = SMb + 49152;
    unsigned char* Madj  = SMb + 65536;     // [64][128B] swz7 bf16 (8K)
    unsigned char* Hp    = SMb + 73728;     // [32][256B] swz15 bf16-hi (rows 24-31 zero)

    const int w = t >> 6, lane = t & 63, g = lane >> 4, lr = lane & 15;
    const int colp = w*16 + lr;

    // ---- ph0: zero Mint / Mocc / Hp pad rows ----
    #pragma unroll
    for (int i = 0; i < 8; ++i) Mint[t + i*512] = 0;
    ((u32*)Mocc)[t] = 0;
    ((u32*)Mocc)[t + 512] = 0;
    ((u32*)(Hp + 6144))[t] = 0;
    __syncthreads();  // B0

    // ---- ph0b: build count matrices ----
    for (int i = t; i < E_ADJ; i += 512) {
        int s = ei_adj[b*E_ADJ + i] - b*SQN;
        int d = ei_adj[E_ADJ_TOT + b*E_ADJ + i] - b*SQN;
        atomicAdd(&Mint[d*64 + s], 1);
    }
    if (t < PCN) {
        int p = ei_occ[b*PCN + t] - b*PCN;
        int d = ei_occ[NPCT + b*PCN + t] - b*SQN;
        *(u16*)(Mocc + d*64 + ((p*2) ^ ((d&3)<<4))) = 0x3F80;  // bf16 1.0
    }
    __syncthreads();  // B1

    // ---- ph1: Mint -> Madj (bf16 swz7) ; input GEMMs -> Hs hi/lo, Hp hi ----
    #pragma unroll
    for (int ii = 0; ii < 4; ++ii) {
        int i = t + ii*512;              // 0..2047 (64 rows x 32 col-pairs)
        int row = i >> 5, cp = i & 31;
        float v0 = (float)Mint[row*64 + cp*2];
        float v1 = (float)Mint[row*64 + cp*2 + 1];
        *(u32*)(Madj + row*128 + ((cp*4) ^ ((row&7)<<4))) = cvtpk(v0, v1);
    }
    float hv[16];   // residual h (post-gelu) kept in registers for epi1
    {
        const f32x4 z = {0.f,0.f,0.f,0.f};
        f32x4 ch[4] = {z,z,z,z};
        {
            bf16x8 bh = *(const bf16x8*)(wb + OFF_WINSQ_H + (w*64 + lane)*8);
            bf16x8 bl = *(const bf16x8*)(wb + OFF_WINSQ_L + (w*64 + lane)*8);
            #pragma unroll
            for (int rt = 0; rt < 4; ++rt) {
                bf16x8 ah = bzero(), al = bzero();
                if (g < 2) xfrag(x_sq + (b*SQN + rt*16 + lr)*FEAT, g, ah, al);
                ch[rt] = MFMA(ah, bh, ch[rt]);
                ch[rt] = MFMA(al, bh, ch[rt]);
                ch[rt] = MFMA(ah, bl, ch[rt]);
            }
        }
        const float bbs = b_in_sq[colp];
        #pragma unroll
        for (int rt = 0; rt < 4; ++rt)
            #pragma unroll
            for (int r = 0; r < 4; ++r) {
                const int row = rt*16 + g*4 + r;
                float h = gelu_f(ch[rt][r] + bbs);
                hv[rt*4 + r] = h;
                u16 hh, ll; split2(h, hh, ll);
                const int bo = row*256 + ((colp*2) ^ ((row&15)<<4));
                *(u16*)(Hs_h + bo) = hh;
                *(u16*)(Hs_l + bo) = ll;
            }
        f32x4 cp2[2] = {z, z};
        {
            bf16x8 bh = *(const bf16x8*)(wb + OFF_WINPC_H + (w*64 + lane)*8);
            bf16x8 bl = *(const bf16x8*)(wb + OFF_WINPC_L + (w*64 + lane)*8);
            #pragma unroll
            for (int rt = 0; rt < 2; ++rt) {
                const int row = rt*16 + lr;
                bf16x8 ah = bzero(), al = bzero();
                if (g < 2 && row < PCN) xfrag(x_pc + (b*PCN + row)*FEAT, g, ah, al);
                cp2[rt] = MFMA(ah, bh, cp2[rt]);
                cp2[rt] = MFMA(al, bh, cp2[rt]);
                cp2[rt] = MFMA(ah, bl, cp2[rt]);
            }
        }
        const float bbp = b_in_pc[colp];
        #pragma unroll
        for (int rt = 0; rt < 2; ++rt)
            #pragma unroll
            for (int r = 0; r < 4; ++r) {
                const int row = rt*16 + g*4 + r;
                if (row < PCN) {
                    float h = gelu_f(cp2[rt][r] + bbp);
                    *(u16*)(Hp + row*256 + ((colp*2) ^ ((row&15)<<4))) = f2b(h);
                }
            }
    }
    __syncthreads();  // B2

    // ---- ph5: HW GEMMs (HW_adj = h_sq@W_adj 3-term; HW_occ = h_pc@W_occ 2-term) ----
    f32x4 hwj[4], hwo[2];
    {
        const f32x4 z = {0.f,0.f,0.f,0.f};
        hwj[0]=z; hwj[1]=z; hwj[2]=z; hwj[3]=z; hwo[0]=z; hwo[1]=z;
        const int sw15 = lr << 4;
        #pragma unroll
        for (int ks = 0; ks < 4; ++ks) {
            const int ko = (ks*64 + g*16) ^ sw15;
            bf16x8 bh = *(const bf16x8*)(wb + OFF_WADJ_H + ((w*4 + ks)*64 + lane)*8);
            bf16x8 bl = *(const bf16x8*)(wb + OFF_WADJ_L + ((w*4 + ks)*64 + lane)*8);
            #pragma unroll
            for (int rt = 0; rt < 4; ++rt) {
                const int ro = (rt*16 + lr)*256 + ko;
                bf16x8 ah = *(const bf16x8*)(Hs_h + ro);
                bf16x8 al = *(const bf16x8*)(Hs_l + ro);
                hwj[rt] = MFMA(ah, bh, hwj[rt]);
                hwj[rt] = MFMA(al, bh, hwj[rt]);
                hwj[rt] = MFMA(ah, bl, hwj[rt]);
            }
            bf16x8 oh = *(const bf16x8*)(wb + OFF_WOCC_H + ((w*4 + ks)*64 + lane)*8);
            bf16x8 ol = *(const bf16x8*)(wb + OFF_WOCC_L + ((w*4 + ks)*64 + lane)*8);
            #pragma unroll
            for (int rt = 0; rt < 2; ++rt) {
                const int ro = (rt*16 + lr)*256 + ko;
                bf16x8 ah = *(const bf16x8*)(Hp + ro);
                hwo[rt] = MFMA(ah, oh, hwo[rt]);
                hwo[rt] = MFMA(ah, ol, hwo[rt]);
            }
        }
    }
    __syncthreads();  // B3 (all Hs/Hp reads done)

    // ---- ph5b: write HWadjT (over Hs) + HWoccT, both transposed [j][s] ----
    {
        const int swj = (lr & 7) << 4;
        #pragma unroll
        for (int rt = 0; rt < 4; ++rt) {
            u32 h01, l01, h23, l23;
            split_pk(hwj[rt][0], hwj[rt][1], h01, l01);
            split_pk(hwj[rt][2], hwj[rt][3], h23, l23);
            const int off = colp*128 + ((rt*32 + g*8) ^ swj);
            *(u32x2*)(Hs_h + off) = (u32x2){h01, h23};
            *(u32x2*)(Hs_l + off) = (u32x2){l01, l23};
        }
        const int swo = (lr & 3) << 4;
        #pragma unroll
        for (int rt = 0; rt < 2; ++rt) {
            u32 h01, l01, h23, l23;
            split_pk(hwo[rt][0], hwo[rt][1], h01, l01);
            split_pk(hwo[rt][2], hwo[rt][3], h23, l23);
            const int off = colp*64 + ((rt*32 + g*8) ^ swo);
            *(u32x2*)(HOT_h + off) = (u32x2){h01, h23};
            *(u32x2*)(HOT_l + off) = (u32x2){l01, l23};
        }
    }
    __syncthreads();  // B4

    // ---- ph6: M-GEMMs: c1 = M_adj@HWadjT + M_occ@HWoccT ----
    f32x4 c1[4];
    {
        const f32x4 z = {0.f,0.f,0.f,0.f};
        c1[0]=z; c1[1]=z; c1[2]=z; c1[3]=z;
        const int swj = (lr & 7) << 4;
        #pragma unroll
        for (int ks = 0; ks < 2; ++ks) {
            const int bo = colp*128 + ((ks*64 + g*16) ^ swj);
            bf16x8 bh = *(const bf16x8*)(Hs_h + bo);
            bf16x8 bl = *(const bf16x8*)(Hs_l + bo);
            #pragma unroll
            for (int rt = 0; rt < 4; ++rt) {
                const int ao = (rt*16 + lr)*128 + ((ks*64 + g*16) ^ swj);
                bf16x8 am = *(const bf16x8*)(Madj + ao);
                c1[rt] = MFMA(am, bh, c1[rt]);
                c1[rt] = MFMA(am, bl, c1[rt]);
            }
        }
        const int swo = (lr & 3) << 4;
        {
            const int bo = colp*64 + ((g*16) ^ swo);
            bf16x8 bh = *(const bf16x8*)(HOT_h + bo);
            bf16x8 bl = *(const bf16x8*)(HOT_l + bo);
            #pragma unroll
            for (int rt = 0; rt < 4; ++rt) {
                const int ao = (rt*16 + lr)*64 + ((g*16) ^ swo);
                bf16x8 am = *(const bf16x8*)(Mocc + ao);
                c1[rt] = MFMA(am, bh, c1[rt]);
                c1[rt] = MFMA(am, bl, c1[rt]);
            }
        }
    }
    __syncthreads();  // B5

    // ---- epi1: h2 = gelu(c1 + h) -> A hi/lo (residual from registers) ----
    #pragma unroll
    for (int rt = 0; rt < 4; ++rt)
        #pragma unroll
        for (int r = 0; r < 4; ++r) {
            const int row = rt*16 + g*4 + r;
            float h2 = gelu_f(c1[rt][r] + hv[rt*4 + r]);
            u16 hh, ll; split2(h2, hh, ll);
            const int bo = row*256 + ((colp*2) ^ ((row&15)<<4));
            *(u16*)(A_h + bo) = hh;
            *(u16*)(A_l + bo) = ll;
        }
    __syncthreads();  // B6

    // ---- GEMM2 (W_out, 2 ntiles/wave) + colsum/64 ----
    f32x4 c2[2][4];
    {
        const f32x4 z = {0.f,0.f,0.f,0.f};
        #pragma unroll
        for (int n = 0; n < 2; ++n)
            #pragma unroll
            for (int rt = 0; rt < 4; ++rt) c2[n][rt] = z;
    }
    gemm_nt<2,4>(A_h, A_l, wb + OFF_WOUT_H, wb + OFF_WOUT_L, w*2, lane, g, lr, c2);
    #pragma unroll
    for (int ntl = 0; ntl < 2; ++ntl) {
        const int col = (w*2 + ntl)*16 + lr;
        const float bias = b_out[col];
        float cs = 0.f;
        #pragma unroll
        for (int rt = 0; rt < 4; ++rt)
            #pragma unroll
            for (int r = 0; r < 4; ++r) cs += gelu_f(c2[ntl][rt][r] + bias);
        cs += __shfl_xor(cs, 16);
        cs += __shfl_xor(cs, 32);
        if (lane < 16) shared_sq[b*DOUT + col] = cs * (1.0f/64.0f);
    }
}

// ---------------------------------------------------------------------------
// piece-path (512 threads, 2 batches/block)
// ---------------------------------------------------------------------------
__device__ __forceinline__ void pc_path(
    unsigned char* SMb, int pcb, int t,
    const float* __restrict__ x_sq, const float* __restrict__ x_pc,
    const float* __restrict__ b_in_sq, const float* __restrict__ b_in_pc,
    const float* __restrict__ b_out,
    const int* __restrict__ ei_att, const int* __restrict__ ei_def,
    const int* __restrict__ ei_rev,
    const u16* __restrict__ wb, float* __restrict__ shared_pc)
{
    unsigned char* Hp = SMb + PHP_OFF;
    unsigned char* Ah = SMb + PAH_OFF;
    unsigned char* Al = SMb + PAL_OFF;
    int* ea_pk = (int*)(SMb + PEA_OFF);
    int* ed_pk = (int*)(SMb + PED_OFF);
    int* srt_a = (int*)(SMb + PSA_OFF);
    int* srt_d = (int*)(SMb + PSD_OFF);
    int* rs_a  = (int*)(SMb + PRSA_OFF);
    int* cur_a = (int*)(SMb + PCUA_OFF);
    int* cnt_a = (int*)(SMb + PCNA_OFF);
    int* rs_d  = (int*)(SMb + PRSD_OFF);
    int* cur_d = (int*)(SMb + PCUD_OFF);
    int* cnt_d = (int*)(SMb + PCND_OFF);
    int* rv_s  = (int*)(SMb + PRVS_OFF);
    int* rv_d  = (int*)(SMb + PRVD_OFF);

    const int w = t >> 6, lane = t & 63, g = lane >> 4, lr = lane & 15;
    const int NR = 2*PCN;   // 48

    for (int i = t; i < 2*E_ATT; i += 512) {
        int sb = (i >= E_ATT) ? 1 : 0;
        int e = i - sb*E_ATT;
        int gb = pcb*2 + sb;
        int ro = sb*PCN - gb*PCN;
        int s = ei_att[gb*E_ATT + e] + ro;
        int d = ei_att[E_ATT_TOT + gb*E_ATT + e] + ro;
        ea_pk[i] = s | (d << 16);
        s = ei_def[gb*E_ATT + e] + ro;
        d = ei_def[E_ATT_TOT + gb*E_ATT + e] + ro;
        ed_pk[i] = s | (d << 16);
    }
    if (t < NR) {
        int sb = (t >= PCN) ? 1 : 0;
        int gb = pcb*2 + sb;
        int p = t - sb*PCN;
        rv_s[t] = ei_rev[gb*PCN + p];
        rv_d[t] = ei_rev[NPCT + gb*PCN + p] - gb*PCN + sb*PCN;
    }
    if (t < 64) { cnt_a[t] = 0; cnt_d[t] = 0; }
    __syncthreads();

    for (int i = t; i < 2*E_ATT; i += 512) {
        atomicAdd(&cnt_a[ea_pk[i] >> 16], 1);
        atomicAdd(&cnt_d[ed_pk[i] >> 16], 1);
    }
    __syncthreads();

    if (t < 64) {
        int v = cnt_a[t], o0 = v;
        for (int o = 1; o < 64; o <<= 1) { int u = __shfl_up(v, o); if (t >= o) v += u; }
        rs_a[t+1] = v; cur_a[t] = v - o0; if (t == 0) rs_a[0] = 0;
    } else if (t < 128) {
        int l = t - 64;
        int v = cnt_d[l], o0 = v;
        for (int o = 1; o < 64; o <<= 1) { int u = __shfl_up(v, o); if (l >= o) v += u; }
        rs_d[l+1] = v; cur_d[l] = v - o0; if (l == 0) rs_d[0] = 0;
    }
    __syncthreads();

    for (int i = t; i < 2*E_ATT; i += 512) {
        int pk = ea_pk[i];
        int p = atomicAdd(&cur_a[pk >> 16], 1); srt_a[p] = pk & 0xffff;
        pk = ed_pk[i];
        p = atomicAdd(&cur_d[pk >> 16], 1); srt_d[p] = pk & 0xffff;
    }
    float hv[8];
    {
        const int colp = w*16 + lr;
        const f32x4 z = {0.f,0.f,0.f,0.f};
        f32x4 cp[3] = {z,z,z};
        {
            bf16x8 bh = *(const bf16x8*)(wb + OFF_WINPC_H + (w*64 + lane)*8);
            bf16x8 bl = *(const bf16x8*)(wb + OFF_WINPC_L + (w*64 + lane)*8);
            #pragma unroll
            for (int rt = 0; rt < 3; ++rt) {
                bf16x8 ah = bzero(), al = bzero();
                if (g < 2) xfrag(x_pc + (pcb*NR + rt*16 + lr)*FEAT, g, ah, al);
                cp[rt] = MFMA(ah, bh, cp[rt]);
                cp[rt] = MFMA(al, bh, cp[rt]);
                cp[rt] = MFMA(ah, bl, cp[rt]);
            }
        }
        const float bbp = b_in_pc[colp];
        #pragma unroll
        for (int rt = 0; rt < 3; ++rt)
            #pragma unroll
            for (int r = 0; r < 4; ++r) {
                const int row = rt*16 + g*4 + r;
                float h = gelu_f(cp[rt][r] + bbp);
                *(float*)(Hp + row*512 + ((colp*4) ^ ((row&15)<<4))) = h;
            }
        f32x4 cr[3] = {z,z,z};
        {
            bf16x8 bh = *(const bf16x8*)(wb + OFF_WINSQ_H + (w*64 + lane)*8);
            bf16x8 bl = *(const bf16x8*)(wb + OFF_WINSQ_L + (w*64 + lane)*8);
            #pragma unroll
            for (int rt = 0; rt < 3; ++rt) {
                bf16x8 ah = bzero(), al = bzero();
                if (g < 2) {
                    int gr = rv_s[rt*16 + lr];
                    xfrag(x_sq + gr*FEAT, g, ah, al);
                }
                cr[rt] = MFMA(ah, bh, cr[rt]);
                cr[rt] = MFMA(al, bh, cr[rt]);
                cr[rt] = MFMA(ah, bl, cr[rt]);
            }
        }
        const float bbs = b_in_sq[colp];
        #pragma unroll
        for (int rt = 0; rt < 3; ++rt)
            #pragma unroll
            for (int r = 0; r < 4; ++r) {
                const int row0 = rt*16 + g*4 + r;
                const int dr = rv_d[row0];
                float h = gelu_f(cr[rt][r] + bbs);
                u16 hh, ll; split2(h, hh, ll);
                const int bo = dr*256 + ((colp*2) ^ ((dr&15)<<4));
                *(u16*)(Ah + bo) = hh;
                *(u16*)(Al + bo) = ll;
            }
    }
    __syncthreads();

    f32x4 c1[1][3];
    {
        const f32x4 z = {0.f,0.f,0.f,0.f};
        #pragma unroll
        for (int rt = 0; rt < 3; ++rt) c1[0][rt] = z;
    }
    gemm_nt<1,3>(Ah, Al, wb + OFF_WREV_H, wb + OFF_WREV_L, w, lane, g, lr, c1);
    __syncthreads();

    {
        const int d = t >> 3, cq8 = t & 7;
        if (d < NR) {
            float acc[16];
            #pragma unroll
            for (int i = 0; i < 16; ++i) acc[i] = 0.f;
            gather_f32_8(Hp, srt_a, rs_a[d], rs_a[d+1], cq8, acc);
            writeA_8(Ah, Al, d, cq8, acc);
        }
    }
    __syncthreads();

    gemm_nt<1,3>(Ah, Al, wb + OFF_WATT_H, wb + OFF_WATT_L, w, lane, g, lr, c1);
    __syncthreads();

    {
        const int d = t >> 3, cq8 = t & 7;
        if (d < NR) {
            float acc[16];
            #pragma unroll
            for (int i = 0; i < 16; ++i) acc[i] = 0.f;
            gather_f32_8(Hp, srt_d, rs_d[d], rs_d[d+1], cq8, acc);
            writeA_8(Ah, Al, d, cq8, acc);
        }
    }
    __syncthreads();

    gemm_nt<1,3>(Ah, Al, wb + OFF_WDEF_H, wb + OFF_WDEF_L, w, lane, g, lr, c1);
    __syncthreads();

    {
        const int colp = w*16 + lr;
        #pragma unroll
        for (int rt = 0; rt < 3; ++rt)
            #pragma unroll
            for (int r = 0; r < 4; ++r) {
                const int row = rt*16 + g*4 + r;
                float hvv = *(const float*)(Hp + row*512 + ((colp*4) ^ ((row&15)<<4)));
                float h2 = gelu_f(c1[0][rt][r] + hvv);
                u16 hh, ll; split2(h2, hh, ll);
                const int bo = row*256 + ((colp*2) ^ ((row&15)<<4));
                *(u16*)(Ah + bo) = hh;
                *(u16*)(Al + bo) = ll;
            }
    }
    __syncthreads();

    f32x4 c2[2][3];
    {
        const f32x4 z = {0.f,0.f,0.f,0.f};
        #pragma unroll
        for (int n = 0; n < 2; ++n)
            #pragma unroll
            for (int rt = 0; rt < 3; ++rt) c2[n][rt] = z;
    }
    gemm_nt<2,3>(Ah, Al, wb + OFF_WOUT_H, wb + OFF_WOUT_L, w*2, lane, g, lr, c2);
    #pragma unroll
    for (int ntl = 0; ntl < 2; ++ntl) {
        const int col = (w*2 + ntl)*16 + lr;
        const float bias = b_out[col];
        float s0 = 0.f, s1 = 0.f;
        #pragma unroll
        for (int r = 0; r < 4; ++r) s0 += gelu_f(c2[ntl][0][r] + bias);
        {
            float tt = 0.f;
            #pragma unroll
            for (int r = 0; r < 4; ++r) tt += gelu_f(c2[ntl][1][r] + bias);
            s0 += (g < 2) ? tt : 0.f;
            s1 += (g < 2) ? 0.f : tt;
        }
        #pragma unroll
        for (int r = 0; r < 4; ++r) s1 += gelu_f(c2[ntl][2][r] + bias);
        s0 += __shfl_xor(s0, 16); s0 += __shfl_xor(s0, 32);
        s1 += __shfl_xor(s1, 16); s1 += __shfl_xor(s1, 32);
        if (lane < 16) {
            const int b0 = pcb*2, b1 = b0 + 1;
            shared_pc[b0*DOUT + col] = s0 * (1.0f/PCN);
            shared_pc[b1*DOUT + col] = s1 * (1.0f/PCN);
        }
    }
}

// ---------------------------------------------------------------------------
__global__ __launch_bounds__(512, 4) void k_main(
    const float* __restrict__ x_sq, const float* __restrict__ x_pc,
    const float* __restrict__ b_in_sq, const float* __restrict__ b_in_pc,
    const float* __restrict__ b_out,
    const int* __restrict__ ei_adj, const int* __restrict__ ei_occ,
    const int* __restrict__ ei_att, const int* __restrict__ ei_def,
    const int* __restrict__ ei_rev,
    const u16* __restrict__ wb,
    float* __restrict__ shared_sq, float* __restrict__ shared_pc)
{
    extern __shared__ __align__(16) unsigned char SMb[];
    const int bid = blockIdx.x;
    const int grp = bid / 3, rem = bid - grp*3;
    if (rem < 2) {
        sq_path(SMb, grp*2 + rem, threadIdx.x, x_sq, x_pc, b_in_sq, b_in_pc,
                b_out, ei_adj, ei_occ, wb, shared_sq);
    } else {
        pc_path(SMb, grp, threadIdx.x, x_sq, x_pc, b_in_sq, b_in_pc,
                b_out, ei_att, ei_def, ei_rev, wb, shared_pc);
    }
}

// ---------------------------------------------------------------------------
// k_head (MFMA): 64 blocks x 32 rows, 512 threads.
// ---------------------------------------------------------------------------
__global__ __launch_bounds__(512) void k_head(
    const float* __restrict__ shared_sq, const float* __restrict__ shared_pc,
    const u16* __restrict__ wb,
    const float* __restrict__ b_pt, const float* __restrict__ b_vt,
    const float* __restrict__ W_vh, const float* __restrict__ b_vh,
    u16* __restrict__ tpol_h, u16* __restrict__ tpol_l, float* __restrict__ out_value)
{
    __shared__ __align__(16) unsigned char SH[33792];
    unsigned char* Ah = SH;             // [32][512B] swz15
    unsigned char* Al = SH + 16384;
    float* vpart = (float*)(SH + 32768);  // [32][8]

    const int t = threadIdx.x;
    const int w = t >> 6, lane = t & 63, g = lane >> 4, lr = lane & 15;
    const int rbase = blockIdx.x * 32;

    // ---- stage S = shared_sq + shared_pc as hi/lo bf16 ----
    {
        const int row = t >> 4, c0 = (t & 15) * 16;
        const float* s1 = shared_sq + (size_t)(rbase + row)*DOUT + c0;
        const float* s2 = shared_pc + (size_t)(rbase + row)*DOUT + c0;
        const int sw = (row & 15) << 4;
        #pragma unroll
        for (int cc = 0; cc < 2; ++cc) {
            f32x4 a = *(const f32x4*)(s1 + cc*8);
            f32x4 b = *(const f32x4*)(s2 + cc*8);
            f32x4 a2 = *(const f32x4*)(s1 + cc*8 + 4);
            f32x4 b2 = *(const f32x4*)(s2 + cc*8 + 4);
            float v0=a[0]+b[0], v1=a[1]+b[1], v2=a[2]+b[2], v3=a[3]+b[3];
            float v4=a2[0]+b2[0], v5=a2[1]+b2[1], v6=a2[2]+b2[2], v7=a2[3]+b2[3];
            u32 h0,h1,h2,h3,l0,l1,l2,l3;
            split_pk(v0,v1,h0,l0); split_pk(v2,v3,h1,l1);
            split_pk(v4,v5,h2,l2); split_pk(v6,v7,h3,l3);
            u32x4 vh = {h0,h1,h2,h3};
            u32x4 vl = {l0,l1,l2,l3};
            *(u32x4*)(Ah + row*512 + ((c0*2 + cc*16) ^ sw)) = vh;
            *(u32x4*)(Al + row*512 + ((c0*2 + cc*16) ^ sw)) = vl;
        }
    }
    __syncthreads();

    // ---- GEMMs: S@W_pt and S@W_vt (K=256, nt=w for both) ----
    f32x4 cpt[2], cvt[2];
    {
        const f32x4 z = {0.f,0.f,0.f,0.f};
        cpt[0]=z; cpt[1]=z; cvt[0]=z; cvt[1]=z;
        const int sw = lr << 4;
        #pragma unroll
        for (int ks = 0; ks < 8; ++ks) {
            const int ko = (ks*64 + g*16) ^ sw;
            bf16x8 ph_ = *(const bf16x8*)(wb + OFF_WPT_H + ((w*8 + ks)*64 + lane)*8);
            bf16x8 pl_ = *(const bf16x8*)(wb + OFF_WPT_L + ((w*8 + ks)*64 + lane)*8);
            bf16x8 vh_ = *(const bf16x8*)(wb + OFF_WVT_H + ((w*8 + ks)*64 + lane)*8);
            bf16x8 vl_ = *(const bf16x8*)(wb + OFF_WVT_L + ((w*8 + ks)*64 + lane)*8);
            #pragma unroll
            for (int rt = 0; rt < 2; ++rt) {
                const int ao = (rt*16 + lr)*512 + ko;
                bf16x8 ah = *(const bf16x8*)(Ah + ao);
                bf16x8 al = *(const bf16x8*)(Al + ao);
                cpt[rt] = MFMA(ah, ph_, cpt[rt]);
                cpt[rt] = MFMA(al, ph_, cpt[rt]);
                cpt[rt] = MFMA(ah, pl_, cpt[rt]);
                cvt[rt] = MFMA(ah, vh_, cvt[rt]);
                cvt[rt] = MFMA(al, vh_, cvt[rt]);
                cvt[rt] = MFMA(ah, vl_, cvt[rt]);
            }
        }
    }

    // ---- epilogues ----
    {
        const int col = w*16 + lr;
        const float bpt = b_pt[col], bvt = b_vt[col], wvh = W_vh[col];
        #pragma unroll
        for (int rt = 0; rt < 2; ++rt)
            #pragma unroll
            for (int r = 0; r < 4; ++r) {
                const int row = rt*16 + g*4 + r;
                float tv = gelu_f(cpt[rt][r] + bpt);
                u16 th, tl; split2(tv, th, tl);
                tpol_h[(size_t)(rbase + row)*TDIM + col] = th;
                tpol_l[(size_t)(rbase + row)*TDIM + col] = tl;
                float vv = gelu_f(cvt[rt][r] + bvt) * wvh;
                vv += __shfl_xor(vv, 1);
                vv += __shfl_xor(vv, 2);
                vv += __shfl_xor(vv, 4);
                vv += __shfl_xor(vv, 8);
                if (lr == 0) vpart[row*8 + w] = vv;
            }
    }
    __syncthreads();
    if (t < 32) {
        float s = 0.f;
        #pragma unroll
        for (int j = 0; j < 8; ++j) s += vpart[t*8 + j];
        out_value[rbase + t] = tanhf(s + b_vh[0]);
    }
}

// ---------------------------------------------------------------------------
// k_pol: policy = tpol @ W_ph + b_ph, split-bf16 MFMA. grid (73, 32).
// ---------------------------------------------------------------------------
__global__ __launch_bounds__(256) void k_pol(
    const u16* __restrict__ tpol_h, const u16* __restrict__ tpol_l,
    const u16* __restrict__ wb, const float* __restrict__ b_ph,
    float* __restrict__ pol)
{
    const u16* wph_h = wb + OFF_WPH_H;
    const u16* wph_l = wb + OFF_WPH_L;
    const int t = threadIdx.x, w = t >> 6, lane = t & 63, g = lane >> 4, lr = lane & 15;
    const int nt = blockIdx.x*4 + w;       // 0..291
    const int rbase = blockIdx.y*64;
    f32x4 acc[4];
    const f32x4 z = {0.f,0.f,0.f,0.f};
    #pragma unroll
    for (int rt = 0; rt < 4; ++rt) acc[rt] = z;
    #pragma unroll
    for (int ks = 0; ks < 4; ++ks) {
        bf16x8 bh = *(const bf16x8*)(wph_h + ((nt*4 + ks)*64 + lane)*8);
        bf16x8 bl = *(const bf16x8*)(wph_l + ((nt*4 + ks)*64 + lane)*8);
        #pragma unroll
        for (int rt = 0; rt < 4; ++rt) {
            const int ro = (rbase + rt*16 + lr)*TDIM + ks*32 + g*8;
            bf16x8 ah = *(const bf16x8*)(tpol_h + ro);
            bf16x8 al = *(const bf16x8*)(tpol_l + ro);
            acc[rt] = MFMA(ah, bh, acc[rt]);
            acc[rt] = MFMA(al, bh, acc[rt]);
            acc[rt] = MFMA(ah, bl, acc[rt]);
        }
    }
    const float bias = b_ph[nt*16 + lr];
    #pragma unroll
    for (int rt = 0; rt < 4; ++rt)
        #pragma unroll
        for (int r = 0; r < 4; ++r) {
            int row = rbase + rt*16 + g*4 + r;
            pol[(size_t)row*ADIM + nt*16 + lr] = acc[rt][r] + bias;
        }
}

// ---------------------------------------------------------------------------
extern "C" void kernel_launch(void* const* d_in, const int* in_sizes, int n_in,
                              void* d_out, int out_size, void* d_ws, size_t ws_size,
                              hipStream_t stream) {
    (void)in_sizes; (void)n_in; (void)out_size; (void)ws_size;
    const float* x_sq    = (const float*)d_in[0];
    const float* x_pc    = (const float*)d_in[1];
    const float* W_in_sq = (const float*)d_in[2];
    const float* b_in_sq = (const float*)d_in[3];
    const float* W_in_pc = (const float*)d_in[4];
    const float* b_in_pc = (const float*)d_in[5];
    const float* W_adj   = (const float*)d_in[6];
    const float* W_occ   = (const float*)d_in[7];
    const float* W_att   = (const float*)d_in[8];
    const float* W_def   = (const float*)d_in[9];
    const float* W_rev   = (const float*)d_in[10];
    const float* W_out   = (const float*)d_in[11];
    const float* b_out   = (const float*)d_in[12];
    const float* W_pt    = (const float*)d_in[13];
    const float* b_pt    = (const float*)d_in[14];
    const float* W_vt    = (const float*)d_in[15];
    const float* b_vt    = (const float*)d_in[16];
    const float* W_ph    = (const float*)d_in[17];
    const float* b_ph    = (const float*)d_in[18];
    const float* W_vh    = (const float*)d_in[19];
    const float* b_vh    = (const float*)d_in[20];
    const int* ei_adj    = (const int*)d_in[21];
    const int* ei_occ    = (const int*)d_in[22];
    const int* ei_att    = (const int*)d_in[23];
    const int* ei_def    = (const int*)d_in[24];
    const int* ei_rev    = (const int*)d_in[25];

    float* out = (float*)d_out;
    float* pol = out;
    float* val = out + (size_t)BATCH * ADIM;

    float* shared_sq = (float*)d_ws;                     // [2048][256] f32
    float* shared_pc = shared_sq + BATCH*DOUT;           // [2048][256] f32
    u16* tpol_h = (u16*)(shared_pc + BATCH*DOUT);        // [2048][128] bf16
    u16* tpol_l = tpol_h + BATCH*TDIM;
    u16* wb     = tpol_l + BATCH*TDIM;                   // WB_TOTAL u16

    hipFuncSetAttribute((const void*)k_main,
                        hipFuncAttributeMaxDynamicSharedMemorySize, K_SMEM);

    k_prep<<<384, 256, 0, stream>>>(W_adj, W_occ, W_att, W_def, W_rev, W_out, W_ph,
                                    W_in_sq, W_in_pc, W_pt, W_vt, wb);
    k_main<<<3072, 512, K_SMEM, stream>>>(x_sq, x_pc, b_in_sq, b_in_pc, b_out,
                                          ei_adj, ei_occ, ei_att, ei_def, ei_rev,
                                          wb, shared_sq, shared_pc);
    k_head<<<64, 512, 0, stream>>>(shared_sq, shared_pc, wb, b_pt, b_vt, W_vh, b_vh,
                                   tpol_h, tpol_l, val);
    k_pol<<<dim3(ADIM/64, BATCH/64), 256, 0, stream>>>(tpol_h, tpol_l, wb, b_ph, pol);
}